// Round 1
// baseline (1301.767 us; speedup 1.0000x reference)
//
#include <hip/hip_runtime.h>
#include <math.h>

#define HH 1024
#define AA 180
#define BB 16
#define NCOL (BB*AA)          // 2880 (b,angle) columns
#define ROWSTRIDE 1032        // padded filtered row stride (16B-aligned data at +4)
#define PI_D 3.14159265358979323846

// ws float-offsets
#define OFF_CG   0                       // 512 filter coeffs
#define OFF_CST  512                     // 360: (512*cos, 512*sin) pairs
#define OFF_XAT  1024                    // NCOL*HH  angle-interp'd transposed sinogram
#define OFF_XAF  (1024 + NCOL*HH)       // NCOL*ROWSTRIDE filtered rows (+guards)

// ---------------- tables ----------------
__global__ __launch_bounds__(512) void k_tables(float* __restrict__ ws) {
    int t = threadIdx.x;
    if (t < 512) {
        double d = 2.0 * t + 1.0;
        ws[OFF_CG + t] = (float)(-2.0 / (PI_D * PI_D * d * d));
    }
    if (t < AA) {
        float thf = (float)t * 0.017453292519943295f;  // fp32(pi/180), matches jnp weak-type mul
        double th = (double)thf;
        ws[OFF_CST + 2*t]     = (float)(512.0 * cos(th));
        ws[OFF_CST + 2*t + 1] = (float)(512.0 * sin(th));
    }
}

// ---------------- angle interp + transpose ----------------
// xat[(b*180+a)*1024 + j] = w0*x[b,j,clip(i0)] + w1*x[b,j,clip(i1)]
__global__ __launch_bounds__(256) void k_interp(const float* __restrict__ x,
                                                float* __restrict__ xat) {
    int col = blockIdx.x;              // b*AA + a
    int b = col / AA, a = col - b * AA;
    float ixf = (float)a * (float)(180.0/179.0) - 0.5f;
    float fl = floorf(ixf);
    int i0 = (int)fl;
    float fx = ixf - fl;
    float w0 = (i0 >= 0)      ? (1.0f - fx) : 0.0f;   // i0 <= 179 always
    float w1 = (i0 + 1 < AA)  ? fx          : 0.0f;   // i1 >= 0  always
    int c0 = max(i0, 0);
    int c1 = min(i0 + 1, AA - 1);
    const float* xb = x + (size_t)b * HH * AA;
    float* dst = xat + (size_t)col * HH;
    int t = threadIdx.x;
    #pragma unroll
    for (int q = 0; q < 4; ++q) {
        int j = q * 256 + t;
        float v0 = xb[j * AA + c0];
        float v1 = xb[j * AA + c1];
        dst[j] = w0 * v0 + w1 * v1;
    }
}

// ---------------- ramp filter: direct odd-tap convolution ----------------
// y[i] = 0.5*x[i] + sum_{odd d=1..1023} c[(d-1)/2]*(x[i-d]+x[i+d]), zero-padded.
// One wave (64 thr) per column; 16 contiguous outputs/thread; ring-buffer
// sliding windows => 4 LDS reads per tap-iteration. LDS swizzled (+1 per 16)
// to kill the stride-16 32-way bank conflict.
__global__ __launch_bounds__(64) void k_filter(const float* __restrict__ cg,
                                               const float* __restrict__ xat,
                                               float* __restrict__ xaf) {
    __shared__ float xsp[3264];        // logical [0..3070] = q+1024, swizzled q->q+(q>>4)
    int t = threadIdx.x;
    int col = blockIdx.x;

    float4* z4 = (float4*)xsp;
    #pragma unroll
    for (int i = t; i < 816; i += 64) z4[i] = make_float4(0.f, 0.f, 0.f, 0.f);
    __syncthreads();
    const float* src = xat + (size_t)col * HH;
    for (int i = t; i < HH; i += 64) {
        int q = 1024 + i;
        xsp[q + (q >> 4)] = src[i];    // lane stride 17 -> conflict-free
    }
    __syncthreads();

    int pp = 17 * t;                   // swizzled base of this thread's p=16t
    float acc[16], Lw[16], Rw[16];
    #pragma unroll
    for (int m = 0; m < 16; ++m) {
        int f = 1024 + m;
        acc[m] = 0.5f * xsp[pp + f + (f >> 4)];
    }
    #pragma unroll
    for (int m = 0; m < 16; ++m) {
        int f = 1 + m;                 // x[p+m-1023]
        Lw[(m + 1) & 15] = xsp[pp + f + (f >> 4)];
        int g = 2047 + m;              // x[p+m+1023]
        Rw[(m - 1) & 15] = xsp[pp + g + (g >> 4)];
    }

    for (int it0 = 0; it0 < 512; it0 += 8) {
        #pragma unroll
        for (int u = 0; u < 8; ++u) {
            int it = it0 + u;          // d = 1023 - 2*it
            float cv = cg[511 - it];   // uniform -> s_load
            #pragma unroll
            for (int m = 0; m < 16; ++m) {
                acc[m] = fmaf(cv, Lw[(m + 2*u + 1) & 15] + Rw[(m - 2*u - 1) & 15], acc[m]);
            }
            int fL  = 2*it + 17;       // next-left elements
            Lw[(2*u + 1) & 15] = xsp[pp + fL  + (fL  >> 4)];
            int fL2 = 2*it + 18;
            Lw[(2*u + 2) & 15] = xsp[pp + fL2 + (fL2 >> 4)];
            int fR  = 2045 - 2*it;     // next-right elements
            Rw[(13 - 2*u) & 15] = xsp[pp + fR  + (fR  >> 4)];
            int fR2 = 2046 - 2*it;
            Rw[(14 - 2*u) & 15] = xsp[pp + fR2 + (fR2 >> 4)];
        }
    }

    float* rp = xaf + (size_t)col * ROWSTRIDE;
    if (t == 0) { rp[3] = 0.f; rp[1028] = 0.f; }   // guards: j=-1 and j=1024
    float4* o4 = (float4*)(rp + 4 + 16 * t);
    #pragma unroll
    for (int m4 = 0; m4 < 4; ++m4)
        o4[m4] = make_float4(acc[4*m4], acc[4*m4+1], acc[4*m4+2], acc[4*m4+3]);
}

// ---------------- backprojection ----------------
__global__ __launch_bounds__(256) void k_bproj(const float* __restrict__ cst,
                                               const float* __restrict__ xaf,
                                               float* __restrict__ out) {
    int tx = threadIdx.x, ty = threadIdx.y;
    int bx = blockIdx.x, by = blockIdx.y, b = blockIdx.z;
    int xg = bx * 16 + tx, yg = by * 16 + ty;
    const float DEL = (float)(2.0 / 1023.0);
    // bit-exact jnp.linspace replication (mul then add, no contraction)
    float ux = __fadd_rn(__fmul_rn((float)xg, DEL), -1.0f);
    float uy = __fadd_rn(__fmul_rn((float)yg, DEL), -1.0f);

    float x0 = __fadd_rn(__fmul_rn((float)(bx*16),      DEL), -1.0f);
    float x1 = __fadd_rn(__fmul_rn((float)(bx*16 + 15), DEL), -1.0f);
    float y0 = __fadd_rn(__fmul_rn((float)(by*16),      DEL), -1.0f);
    float y1 = __fadd_rn(__fmul_rn((float)(by*16 + 15), DEL), -1.0f);
    float minax = (x0 <= 0.f && x1 >= 0.f) ? 0.f : fminf(fabsf(x0), fabsf(x1));
    float maxax = fmaxf(fabsf(x0), fabsf(x1));
    float minay = (y0 <= 0.f && y1 >= 0.f) ? 0.f : fminf(fabsf(y0), fabsf(y1));
    float maxay = fmaxf(fabsf(y0), fabsf(y1));
    float rmin2 = minax * minax + minay * minay;
    float rmax2 = maxax * maxax + maxay * maxay;

    size_t oidx = ((size_t)b << 20) + ((size_t)yg << 10) + (size_t)xg;
    if (rmin2 > 1.000001f) { out[oidx] = 0.f; return; }   // tile fully outside

    const float* rp0 = xaf + (size_t)b * (AA * ROWSTRIDE) + 4;
    float nuy = -uy;
    float acc = 0.f;
    const float SC = (float)(PI_D / 360.0);

    if (rmax2 <= 0.9975f) {
        // interior: j0 in [0,1022] guaranteed, no bounds checks, no mask
        #pragma unroll 4
        for (int a = 0; a < AA; ++a) {
            float c = cst[2*a], s = cst[2*a + 1];          // uniform -> s_load
            float iy = fmaf(ux, c, fmaf(nuy, s, 511.5f));  // (T+1)*512-0.5
            float jf = floorf(iy);
            int j0 = (int)jf;
            float fy = iy - jf;
            const float* rp = rp0 + a * ROWSTRIDE;
            float v0 = rp[j0];
            float v1 = rp[j0 + 1];
            acc = fmaf(fy, v1 - v0, acc + v0);
        }
        out[oidx] = acc * SC;
    } else {
        // rim tiles: full bounds handling via guard pads + zeroed weights
        #pragma unroll 2
        for (int a = 0; a < AA; ++a) {
            float c = cst[2*a], s = cst[2*a + 1];
            float iy = fmaf(ux, c, fmaf(nuy, s, 511.5f));
            float jf = floorf(iy);
            int j0 = (int)jf;
            float fy = iy - jf;
            int jc = max(-1, min(j0, 1023));
            const float* rp = rp0 + a * ROWSTRIDE;
            float v0 = rp[jc];
            float v1 = rp[jc + 1];
            float u0 = ((unsigned)j0       < 1024u) ? (1.0f - fy) : 0.0f;
            float u1 = ((unsigned)(j0 + 1) < 1024u) ? fy          : 0.0f;
            acc = fmaf(v0, u0, acc);
            acc = fmaf(v1, u1, acc);
        }
        float r2 = __fadd_rn(__fmul_rn(ux, ux), __fmul_rn(uy, uy));  // bit-exact mask
        out[oidx] = (r2 <= 1.0f) ? acc * SC : 0.f;
    }
}

extern "C" void kernel_launch(void* const* d_in, const int* in_sizes, int n_in,
                              void* d_out, int out_size, void* d_ws, size_t ws_size,
                              hipStream_t stream) {
    const float* x = (const float*)d_in[0];
    float* out = (float*)d_out;
    float* ws = (float*)d_ws;
    float* cg  = ws + OFF_CG;
    float* cst = ws + OFF_CST;
    float* xat = ws + OFF_XAT;
    float* xaf = ws + OFF_XAF;

    hipLaunchKernelGGL(k_tables, dim3(1), dim3(512), 0, stream, ws);
    hipLaunchKernelGGL(k_interp, dim3(NCOL), dim3(256), 0, stream, x, xat);
    hipLaunchKernelGGL(k_filter, dim3(NCOL), dim3(64), 0, stream, cg, xat, xaf);
    hipLaunchKernelGGL(k_bproj, dim3(64, 64, BB), dim3(16, 16), 0, stream, cst, xaf, out);
}